// Round 7
// baseline (148.846 us; speedup 1.0000x reference)
//
#include <hip/hip_runtime.h>
#include <hip/hip_bf16.h>

// ItemCodeDPQ: out[b,s, m*16+d] = (input_ids[b,s]==0) ? 0
//            : centroids[m, clamp(item_codes[input_ids[b,s], m], 0, 255), d]
// Shapes: input_ids (1024,200) int, item_codes (1e6,8) i32, centroids (8,256,16) f32
// Output: (1024,200,128) f32.
//
// Hardened: every global index is clamped to its buffer's bounds so no input
// interpretation error can produce an illegal access (wrong layout -> wrong
// values -> absmax diagnostic, not a dead container).

#define PQ_M   8
#define VALS   256
#define SUB    16

__global__ __launch_bounds__(256) void
dpq_kernel(const int* __restrict__ input_ids,
           const int* __restrict__ item_codes,
           const float* __restrict__ centroids,
           float4* __restrict__ out,
           int n_f4,        // total float4 elements of output = out_size/4
           int num_items)   // item_codes rows
{
    int t = blockIdx.x * blockDim.x + threadIdx.x;
    if (t >= n_f4) return;

    const int p = t >> 5;        // position index (b*S + s)
    const int q = t & 31;        // which float4 within the 128-float row

    const int id = input_ids[p]; // broadcast across the 32 lanes of a position

    float4 v = make_float4(0.f, 0.f, 0.f, 0.f);
    if (id != 0) {
        // clamp id for ADDRESSING only (id!=0 test above uses raw value)
        int idc = id;
        idc = idc < 0 ? 0 : (idc >= num_items ? num_items - 1 : idc);
        const int m = q >> 2;    // sub-codebook index 0..7
        int code = item_codes[idc * PQ_M + m];
        code = min(max(code, 0), VALS - 1);
        const float4* crow =
            (const float4*)(centroids + ((size_t)m * VALS + code) * SUB);
        v = crow[q & 3];
    }
    out[t] = v;
}

extern "C" void kernel_launch(void* const* d_in, const int* in_sizes, int n_in,
                              void* d_out, int out_size, void* d_ws, size_t ws_size,
                              hipStream_t stream)
{
    const int*   input_ids  = (const int*)d_in[0];
    const int*   item_codes = (const int*)d_in[1];
    const float* centroids  = (const float*)d_in[2];
    float*       out        = (float*)d_out;

    // Store bound from out_size (authoritative): out_size floats -> /4 float4s.
    const int n_f4      = out_size / 4;
    const int num_items = in_sizes[1] / PQ_M;   // 8e6 / 8 = 1e6

    const int block = 256;
    const int grid  = (n_f4 + block - 1) / block;
    dpq_kernel<<<grid, block, 0, stream>>>(input_ids, item_codes, centroids,
                                           (float4*)out, n_f4, num_items);
}